// Round 1
// baseline (466.341 us; speedup 1.0000x reference)
//
#include <hip/hip_runtime.h>

typedef float  f32x4  __attribute__((ext_vector_type(4)));
typedef __bf16 bf16x8 __attribute__((ext_vector_type(8)));

#define LOG2E      1.4426950408889634f
#define TWO_LOG2E  2.8853900817779268f

__device__ __forceinline__ float fast_tanh(float x) {
    float e = __builtin_amdgcn_exp2f(x * TWO_LOG2E);
    return 1.0f - 2.0f * __builtin_amdgcn_rcpf(e + 1.0f);
}

// A-tile LDS swizzle: chunk(m, k8) for 16B chunk enc[m][k8*8..k8*8+7] (bf16)
//   high = (m>>4)*16 + (k8>>2)          (k8>>2 == s)
//   low6 = ((k8&3)<<4 | (m&15)) ^ ((k8>>2)&7) ^ (((k8&3)<<1)&7)
// MFMA read (lane l, tile mt, step s): low6 = l ^ (s&7) ^ (((l>>4)<<1)&7)
//   -> all 64 lanes distinct (conflict-free).
// Staging write (k8 = q*16+(t&15), m = t>>4 and t>>4+32): bank-low3 =
//   (m&7) ^ ((k8>>2)&7) ^ (((k8&3)<<1)&7) -> distinct within every 8-lane phase.
__device__ __forceinline__ int a_chunk(int m, int k8) {
    return (((m >> 4) * 16 + (k8 >> 2)) << 6) +
           ((((k8 & 3) << 4) | (m & 15)) ^ ((k8 >> 2) & 7) ^ (((k8 & 3) << 1) & 7));
}

// ---------------------------------------------------------------------------
// Prolog (one kernel, 2209 blocks x 256):
//   blocks [0,128)    : W_h fp32 -> bf16 swizzled B-fragment order
//   blocks [128,2176) : q_proj[b][o] = dot(query[b], Wq[o]) (one wave per pair)
//   blocks [2176,2209): zero ctx_acc (8192) + denom (16)
// ---------------------------------------------------------------------------
__global__ void prolog_kernel(const float* __restrict__ Wh,
                              __bf16* __restrict__ Wswz,
                              const float* __restrict__ query,
                              const float* __restrict__ Wq,
                              float* __restrict__ qp,
                              float* __restrict__ ctx_acc,
                              float* __restrict__ denom) {
    const int bid = blockIdx.x;
    const int t   = threadIdx.x;
    if (bid < 128) {
        int gid = (bid << 8) + t;              // 0..32767
        int n   = gid >> 6;
        int k8  = gid & 63;
        const float* g = Wh + ((long)n << 9) + (k8 << 3);
        f32x4 f0 = *(const f32x4*)g;
        f32x4 f1 = *(const f32x4*)(g + 4);
        bf16x8 val;
        val[0] = (__bf16)f0[0]; val[1] = (__bf16)f0[1];
        val[2] = (__bf16)f0[2]; val[3] = (__bf16)f0[3];
        val[4] = (__bf16)f1[0]; val[5] = (__bf16)f1[1];
        val[6] = (__bf16)f1[2]; val[7] = (__bf16)f1[3];
        int chunk = (((n >> 4) * 16 + (k8 >> 2)) << 6) + (((k8 & 3) << 4) | (n & 15));
        *(bf16x8*)(Wswz + ((long)chunk << 3)) = val;
    } else if (bid < 2176) {
        int pair = ((bid - 128) << 2) + (t >> 6);    // 0..8191 = b*512+o
        int l    = t & 63;
        int b    = pair >> 9;
        long o   = pair & 511;
        const f32x4* q  = (const f32x4*)(query + (b << 9) + (l << 3));
        const f32x4* wr = (const f32x4*)(Wq + (o << 9) + (l << 3));
        f32x4 a0 = q[0], a1 = q[1], w0 = wr[0], w1 = wr[1];
        float acc = a0[0]*w0[0] + a0[1]*w0[1] + a0[2]*w0[2] + a0[3]*w0[3]
                  + a1[0]*w1[0] + a1[1]*w1[1] + a1[2]*w1[2] + a1[3]*w1[3];
        #pragma unroll
        for (int off = 1; off < 64; off <<= 1) acc += __shfl_xor(acc, off, 64);
        if (l == 0) qp[pair] = acc;
    } else {
        int i = ((bid - 2176) << 8) + t;             // 0..8447
        if (i < 8192)      ctx_acc[i] = 0.f;
        else if (i < 8208) denom[i - 8192] = 0.f;
    }
}

// ---------------------------------------------------------------------------
// K2: fused scores + exp + context-partial. Block = 512 threads (8 waves),
// 64 rows of (b,s). Wave w owns N-slice [w*64, w*64+64). LDS ~66 KB ->
// 2 blocks/CU = 16 waves/CU.
//
// NEW: K-split software pipeline. Stage k-half0, cross a RAW s_barrier with
// the k8[32..48) loads still in flight (lgkmcnt-only drain -> no vmcnt(0)
// barrier stall), hide their HBM latency under MFMA s=0..3, write, issue the
// last quarter under s=4..7, lgkmcnt-barrier, then s=8..15 on half1.
// Held regs per quarter = 4 x f32x4 = 16 VGPR (peak stays under the 128 cap).
// ---------------------------------------------------------------------------
__global__ __launch_bounds__(512, 4) void score_ctx_kernel(
    const float*  __restrict__ enc,
    const __bf16* __restrict__ Wswz,
    const float*  __restrict__ qp,
    const float*  __restrict__ v,
    float* __restrict__ alpha_out,   // (B*S) unnormalized e^score
    float* __restrict__ ctx_acc,     // (B*H) atomic accumulation
    float* __restrict__ denom)       // (B)   atomic accumulation
{
    __shared__ __align__(16) unsigned char ldsA[65536]; // 64 rows x 512 k bf16, swizzled
    __shared__ float score_lds[512];                    // [wave][64 rows]
    __shared__ float escore[64];

    const int  t    = threadIdx.x;
    const int  w    = t >> 6;        // wave id = N-slice owner
    const int  l    = t & 63;
    const long row0 = (long)blockIdx.x << 6;
    const int  b    = (int)(row0 >> 13);

    // ---- acc init = q_proj[b][n]; v fragment ----
    f32x4 acc[4][4];     // [nt][mt]
    float vv[4];
    #pragma unroll
    for (int nt = 0; nt < 4; ++nt) {
        int n = (w << 6) + (nt << 4) + (l & 15);
        float q = qp[(b << 9) + n];
        vv[nt] = v[n];
        f32x4 qv = {q, q, q, q};
        #pragma unroll
        for (int mt = 0; mt < 4; ++mt) acc[nt][mt] = qv;
    }

    // ---- staging helpers: quarter q covers k8 in [q*16, q*16+16), rows
    //      sm and sm+32; per thread 2 chunks = 4 f32x4 loads ----
    const int sk8 = t & 15;
    const int sm  = t >> 4;                       // 0..31
    const float* gbase = enc + ((row0 + sm) << 9);

    auto ld_q = [&](int q8, f32x4* F) {
        const float* g0 = gbase + (((q8 << 4) | sk8) << 3);
        F[0] = *(const f32x4*)g0;
        F[1] = *(const f32x4*)(g0 + 4);
        const float* g1 = g0 + (32 << 9);
        F[2] = *(const f32x4*)g1;
        F[3] = *(const f32x4*)(g1 + 4);
    };
    auto wr_q = [&](int q8, f32x4* F) {
        int k8 = (q8 << 4) | sk8;
        bf16x8 v0, v1;
        v0[0] = (__bf16)F[0][0]; v0[1] = (__bf16)F[0][1];
        v0[2] = (__bf16)F[0][2]; v0[3] = (__bf16)F[0][3];
        v0[4] = (__bf16)F[1][0]; v0[5] = (__bf16)F[1][1];
        v0[6] = (__bf16)F[1][2]; v0[7] = (__bf16)F[1][3];
        v1[0] = (__bf16)F[2][0]; v1[1] = (__bf16)F[2][1];
        v1[2] = (__bf16)F[2][2]; v1[3] = (__bf16)F[2][3];
        v1[4] = (__bf16)F[3][0]; v1[5] = (__bf16)F[3][1];
        v1[6] = (__bf16)F[3][2]; v1[7] = (__bf16)F[3][3];
        *(bf16x8*)(ldsA + (a_chunk(sm,      k8) << 4)) = v0;
        *(bf16x8*)(ldsA + (a_chunk(sm + 32, k8) << 4)) = v1;
    };

    const bf16x8* Bg = (const bf16x8*)Wswz;
    auto kstep = [&](int s) {
        bf16x8 af[4];
        int lowr = l ^ (s & 7) ^ (((l >> 4) << 1) & 7);
        #pragma unroll
        for (int mt = 0; mt < 4; ++mt)
            af[mt] = *(const bf16x8*)(ldsA + (((((mt << 4) + s) << 6) + lowr) << 4));
        #pragma unroll
        for (int nt = 0; nt < 4; ++nt) {
            bf16x8 bf = Bg[((((w << 2) + nt) * 16 + s) << 6) + l];
            #pragma unroll
            for (int mt = 0; mt < 4; ++mt)
                acc[nt][mt] = __builtin_amdgcn_mfma_f32_16x16x32_bf16(
                    af[mt], bf, acc[nt][mt], 0, 0, 0);
        }
    };

    // ---- pipelined stage + K-loop ----
    f32x4 RA[4], RB[4];
    ld_q(0, RA); ld_q(1, RB);      // half0: two batches in flight
    wr_q(0, RA); wr_q(1, RB);
    ld_q(2, RA);                   // quarter 2 loads cross the barrier in flight

    asm volatile("s_waitcnt lgkmcnt(0)" ::: "memory");  // half0 ds_writes done
    __builtin_amdgcn_s_barrier();                        // NO vmcnt drain
    __builtin_amdgcn_sched_barrier(0);

    #pragma unroll
    for (int s = 0; s < 4; ++s) kstep(s);   // half0 MFMA covers q2 HBM latency
    wr_q(2, RA);
    ld_q(3, RB);
    #pragma unroll
    for (int s = 4; s < 8; ++s) kstep(s);   // covers q3 HBM latency
    wr_q(3, RB);

    asm volatile("s_waitcnt lgkmcnt(0)" ::: "memory");  // half1 ds_writes done
    __builtin_amdgcn_s_barrier();
    __builtin_amdgcn_sched_barrier(0);

    #pragma unroll 2
    for (int s = 8; s < 16; ++s) kstep(s);

    // ---- epilogue: per-row score partials over this wave's 64-col slice ----
    float srow[16];
    #pragma unroll
    for (int i = 0; i < 16; ++i) srow[i] = 0.f;
    #pragma unroll
    for (int nt = 0; nt < 4; ++nt) {
        float vn = vv[nt];
        #pragma unroll
        for (int mt = 0; mt < 4; ++mt)
            #pragma unroll
            for (int r = 0; r < 4; ++r)
                srow[mt * 4 + r] += vn * fast_tanh(acc[nt][mt][r]);
    }
    #pragma unroll
    for (int i = 0; i < 16; ++i) {
        #pragma unroll
        for (int off = 1; off < 16; off <<= 1)
            srow[i] += __shfl_xor(srow[i], off, 64);
    }
    if ((l & 15) == 0) {
        int qd = l >> 4;
        #pragma unroll
        for (int mt = 0; mt < 4; ++mt)
            #pragma unroll
            for (int r = 0; r < 4; ++r)
                score_lds[(w << 6) + (mt << 4) + (qd << 2) + r] = srow[mt * 4 + r];
    }
    __syncthreads();

    if (t < 64) {   // wave 0: combine 8 wave-slices, exp, alpha, denom
        float sc = 0.f;
        #pragma unroll
        for (int ww = 0; ww < 8; ++ww) sc += score_lds[(ww << 6) + t];
        float e = __builtin_amdgcn_exp2f(sc * LOG2E);
        alpha_out[row0 + t] = e;
        escore[t] = e;
        float ssum = e;
        #pragma unroll
        for (int off = 1; off < 64; off <<= 1) ssum += __shfl_xor(ssum, off, 64);
        if (t == 0) atomicAdd(denom + b, ssum);
    }
    __syncthreads();

    // ---- context partial: wave w handles rows w*8..w*8+7, lane = h-octet ----
    float ca[8];
    #pragma unroll
    for (int j = 0; j < 8; ++j) ca[j] = 0.f;
    #pragma unroll
    for (int ii = 0; ii < 8; ++ii) {
        int m = (w << 3) + ii;
        float em = escore[m];
        bf16x8 av = *(const bf16x8*)(ldsA + (a_chunk(m, l) << 4));
        #pragma unroll
        for (int j = 0; j < 8; ++j) ca[j] += em * (float)av[j];
    }
    __syncthreads();                    // all A reads done -> reuse region
    float* part = (float*)ldsA;         // 512 threads x 8 floats, stride 9
    #pragma unroll
    for (int j = 0; j < 8; ++j) part[t * 9 + j] = ca[j];
    __syncthreads();
    {
        int h = t;                      // 512 threads = 512 h values
        int k8h = h >> 3, j = h & 7;
        float sum = 0.f;
        #pragma unroll
        for (int rg = 0; rg < 8; ++rg) sum += part[((rg << 6) | k8h) * 9 + j];
        atomicAdd(ctx_acc + ((long)b << 9) + h, sum);
    }
}

// ---------------------------------------------------------------------------
// K3: normalize both outputs by denom[b]
// ---------------------------------------------------------------------------
__global__ void normalize_kernel(const float* __restrict__ ctx_acc,
                                 const float* __restrict__ denom,
                                 float* __restrict__ out) {
    int i = blockIdx.x * 256 + threadIdx.x;
    if (i < 8192) {
        int b = i >> 9;
        out[i] = ctx_acc[i] / denom[b];
    } else if (i < 8192 + 131072) {
        int b = (i - 8192) >> 13;
        out[i] = out[i] / denom[b];
    }
}

extern "C" void kernel_launch(void* const* d_in, const int* in_sizes, int n_in,
                              void* d_out, int out_size, void* d_ws, size_t ws_size,
                              hipStream_t stream) {
    const float* enc   = (const float*)d_in[0];  // (16,8192,512)
    const float* query = (const float*)d_in[1];  // (16,512)
    const float* Wh    = (const float*)d_in[2];  // (512,512)
    const float* Wq    = (const float*)d_in[3];  // (512,512)
    const float* v     = (const float*)d_in[4];  // (512,)
    float* out = (float*)d_out;                  // [context 8192 | alpha 131072]

    char* ws = (char*)d_ws;
    float*  ctx_acc = (float*)ws;                // 8192 floats
    float*  denom   = (float*)(ws + 32768);      // 16 floats
    float*  qp      = (float*)(ws + 32832);      // 8192 floats
    __bf16* Wswz    = (__bf16*)(ws + 65600);     // 262144 bf16, 16B aligned

    prolog_kernel<<<2209, 256, 0, stream>>>(Wh, Wswz, query, Wq, qp,
                                            ctx_acc, denom);
    score_ctx_kernel<<<2048, 512, 0, stream>>>(enc, Wswz, qp, v,
                                               out + 8192, ctx_acc, denom);
    normalize_kernel<<<544, 256, 0, stream>>>(ctx_acc, denom, out);
}

// Round 2
// 455.165 us; speedup vs baseline: 1.0246x; 1.0246x over previous
//
#include <hip/hip_runtime.h>

typedef float  f32x4  __attribute__((ext_vector_type(4)));
typedef __bf16 bf16x8 __attribute__((ext_vector_type(8)));

#define LOG2E      1.4426950408889634f
#define TWO_LOG2E  2.8853900817779268f

__device__ __forceinline__ float fast_tanh(float x) {
    float e = __builtin_amdgcn_exp2f(x * TWO_LOG2E);
    return 1.0f - 2.0f * __builtin_amdgcn_rcpf(e + 1.0f);
}

// A-tile LDS swizzle: chunk(m, k8) for 16B chunk enc[m][k8*8..k8*8+7] (bf16)
//   high = (m>>4)*16 + (k8>>2)          (k8>>2 == s)
//   low6 = ((k8&3)<<4 | (m&15)) ^ ((k8>>2)&7) ^ (((k8&3)<<1)&7)
// MFMA read (lane l, tile mt, step s): low6 = l ^ (s&7) ^ (((l>>4)<<1)&7)
//   -> all 64 lanes distinct (conflict-free).
// Staging write (k8 = q*16+(t&15), m = t>>4 and t>>4+32): bank-low3 =
//   (m&7) ^ ((k8>>2)&7) ^ (((k8&3)<<1)&7) -> distinct within every 8-lane phase.
__device__ __forceinline__ int a_chunk(int m, int k8) {
    return (((m >> 4) * 16 + (k8 >> 2)) << 6) +
           ((((k8 & 3) << 4) | (m & 15)) ^ ((k8 >> 2) & 7) ^ (((k8 & 3) << 1) & 7));
}

// ---------------------------------------------------------------------------
// Prolog (one kernel, 2209 blocks x 256):
//   blocks [0,128)    : W_h fp32 -> bf16 swizzled B-fragment order
//   blocks [128,2176) : q_proj[b][o] = dot(query[b], Wq[o]) (one wave per pair)
//   blocks [2176,2209): zero ctx_acc (8192) + denom (16)
// ---------------------------------------------------------------------------
__global__ void prolog_kernel(const float* __restrict__ Wh,
                              __bf16* __restrict__ Wswz,
                              const float* __restrict__ query,
                              const float* __restrict__ Wq,
                              float* __restrict__ qp,
                              float* __restrict__ ctx_acc,
                              float* __restrict__ denom) {
    const int bid = blockIdx.x;
    const int t   = threadIdx.x;
    if (bid < 128) {
        int gid = (bid << 8) + t;              // 0..32767
        int n   = gid >> 6;
        int k8  = gid & 63;
        const float* g = Wh + ((long)n << 9) + (k8 << 3);
        f32x4 f0 = *(const f32x4*)g;
        f32x4 f1 = *(const f32x4*)(g + 4);
        bf16x8 val;
        val[0] = (__bf16)f0[0]; val[1] = (__bf16)f0[1];
        val[2] = (__bf16)f0[2]; val[3] = (__bf16)f0[3];
        val[4] = (__bf16)f1[0]; val[5] = (__bf16)f1[1];
        val[6] = (__bf16)f1[2]; val[7] = (__bf16)f1[3];
        int chunk = (((n >> 4) * 16 + (k8 >> 2)) << 6) + (((k8 & 3) << 4) | (n & 15));
        *(bf16x8*)(Wswz + ((long)chunk << 3)) = val;
    } else if (bid < 2176) {
        int pair = ((bid - 128) << 2) + (t >> 6);    // 0..8191 = b*512+o
        int l    = t & 63;
        int b    = pair >> 9;
        long o   = pair & 511;
        const f32x4* q  = (const f32x4*)(query + (b << 9) + (l << 3));
        const f32x4* wr = (const f32x4*)(Wq + (o << 9) + (l << 3));
        f32x4 a0 = q[0], a1 = q[1], w0 = wr[0], w1 = wr[1];
        float acc = a0[0]*w0[0] + a0[1]*w0[1] + a0[2]*w0[2] + a0[3]*w0[3]
                  + a1[0]*w1[0] + a1[1]*w1[1] + a1[2]*w1[2] + a1[3]*w1[3];
        #pragma unroll
        for (int off = 1; off < 64; off <<= 1) acc += __shfl_xor(acc, off, 64);
        if (l == 0) qp[pair] = acc;
    } else {
        int i = ((bid - 2176) << 8) + t;             // 0..8447
        if (i < 8192)      ctx_acc[i] = 0.f;
        else if (i < 8208) denom[i - 8192] = 0.f;
    }
}

// ---------------------------------------------------------------------------
// K2: fused scores + exp + context-partial. Block = 512 threads (8 waves),
// 64 rows of (b,s). Wave w owns N-slice [w*64, w*64+64). LDS ~66 KB ->
// 2 blocks/CU = 16 waves/CU.
//
// Split-K software pipeline (R2: NAMED registers -- R1's f32x4 arrays passed
// by pointer through lambdas spilled to scratch: WRITE_SIZE 4.6->214 MB,
// +300 MB HBM traffic. Macros + named f32x4 keep everything in VGPRs).
// Stage k-half0, cross a RAW s_barrier with the quarter-2 loads still in
// flight (lgkmcnt-only drain, never vmcnt(0)), hide their HBM latency under
// MFMA s=0..3, write, issue quarter-3 under s=4..7, lgkmcnt-barrier, s=8..15.
// ---------------------------------------------------------------------------
__global__ __launch_bounds__(512, 4) void score_ctx_kernel(
    const float*  __restrict__ enc,
    const __bf16* __restrict__ Wswz,
    const float*  __restrict__ qp,
    const float*  __restrict__ v,
    float* __restrict__ alpha_out,   // (B*S) unnormalized e^score
    float* __restrict__ ctx_acc,     // (B*H) atomic accumulation
    float* __restrict__ denom)       // (B)   atomic accumulation
{
    __shared__ __align__(16) unsigned char ldsA[65536]; // 64 rows x 512 k bf16, swizzled
    __shared__ float score_lds[512];                    // [wave][64 rows]
    __shared__ float escore[64];

    const int  t    = threadIdx.x;
    const int  w    = t >> 6;        // wave id = N-slice owner
    const int  l    = t & 63;
    const long row0 = (long)blockIdx.x << 6;
    const int  b    = (int)(row0 >> 13);

    // ---- acc init = q_proj[b][n]; v fragment ----
    f32x4 acc[4][4];     // [nt][mt]
    float vv[4];
    #pragma unroll
    for (int nt = 0; nt < 4; ++nt) {
        int n = (w << 6) + (nt << 4) + (l & 15);
        float q = qp[(b << 9) + n];
        vv[nt] = v[n];
        f32x4 qv = {q, q, q, q};
        #pragma unroll
        for (int mt = 0; mt < 4; ++mt) acc[nt][mt] = qv;
    }

    // ---- staging: quarter q covers k8 in [q*16, q*16+16), rows sm, sm+32 ----
    const int sk8 = t & 15;
    const int sm  = t >> 4;                       // 0..31
    const float* gbase = enc + ((row0 + sm) << 9);

#define LD_Q(q8, F0, F1, F2, F3)                                   \
    {                                                              \
        const float* g0 = gbase + ((((q8) << 4) | sk8) << 3);      \
        F0 = *(const f32x4*)g0;                                    \
        F1 = *(const f32x4*)(g0 + 4);                              \
        const float* g1 = g0 + (32 << 9);                          \
        F2 = *(const f32x4*)g1;                                    \
        F3 = *(const f32x4*)(g1 + 4);                              \
    }

#define WR_Q(q8, F0, F1, F2, F3)                                   \
    {                                                              \
        int k8w = ((q8) << 4) | sk8;                               \
        bf16x8 v0, v1;                                             \
        v0[0] = (__bf16)F0[0]; v0[1] = (__bf16)F0[1];              \
        v0[2] = (__bf16)F0[2]; v0[3] = (__bf16)F0[3];              \
        v0[4] = (__bf16)F1[0]; v0[5] = (__bf16)F1[1];              \
        v0[6] = (__bf16)F1[2]; v0[7] = (__bf16)F1[3];              \
        v1[0] = (__bf16)F2[0]; v1[1] = (__bf16)F2[1];              \
        v1[2] = (__bf16)F2[2]; v1[3] = (__bf16)F2[3];              \
        v1[4] = (__bf16)F3[0]; v1[5] = (__bf16)F3[1];              \
        v1[6] = (__bf16)F3[2]; v1[7] = (__bf16)F3[3];              \
        *(bf16x8*)(ldsA + (a_chunk(sm,      k8w) << 4)) = v0;      \
        *(bf16x8*)(ldsA + (a_chunk(sm + 32, k8w) << 4)) = v1;      \
    }

    const bf16x8* Bg = (const bf16x8*)Wswz;
    auto kstep = [&](int s) {
        bf16x8 af[4];
        int lowr = l ^ (s & 7) ^ (((l >> 4) << 1) & 7);
        #pragma unroll
        for (int mt = 0; mt < 4; ++mt)
            af[mt] = *(const bf16x8*)(ldsA + (((((mt << 4) + s) << 6) + lowr) << 4));
        #pragma unroll
        for (int nt = 0; nt < 4; ++nt) {
            bf16x8 bf = Bg[((((w << 2) + nt) * 16 + s) << 6) + l];
            #pragma unroll
            for (int mt = 0; mt < 4; ++mt)
                acc[nt][mt] = __builtin_amdgcn_mfma_f32_16x16x32_bf16(
                    af[mt], bf, acc[nt][mt], 0, 0, 0);
        }
    };

    // ---- pipelined stage + K-loop ----
    f32x4 A0, A1, A2, A3;   // quarter batch A
    f32x4 B0, B1, B2, B3;   // quarter batch B
    LD_Q(0, A0, A1, A2, A3);
    LD_Q(1, B0, B1, B2, B3);
    WR_Q(0, A0, A1, A2, A3);
    WR_Q(1, B0, B1, B2, B3);
    LD_Q(2, A0, A1, A2, A3);             // crosses the barrier in flight

    asm volatile("s_waitcnt lgkmcnt(0)" ::: "memory");  // half0 ds_writes done
    __builtin_amdgcn_s_barrier();                        // NO vmcnt drain
    __builtin_amdgcn_sched_barrier(0);

    kstep(0); kstep(1); kstep(2); kstep(3);  // half0 MFMA covers q2 HBM latency
    WR_Q(2, A0, A1, A2, A3);
    LD_Q(3, B0, B1, B2, B3);
    kstep(4); kstep(5); kstep(6); kstep(7);  // covers q3 HBM latency
    WR_Q(3, B0, B1, B2, B3);

    asm volatile("s_waitcnt lgkmcnt(0)" ::: "memory");  // half1 ds_writes done
    __builtin_amdgcn_s_barrier();
    __builtin_amdgcn_sched_barrier(0);

    #pragma unroll 2
    for (int s = 8; s < 16; ++s) kstep(s);

    // ---- epilogue: per-row score partials over this wave's 64-col slice ----
    float srow[16];
    #pragma unroll
    for (int i = 0; i < 16; ++i) srow[i] = 0.f;
    #pragma unroll
    for (int nt = 0; nt < 4; ++nt) {
        float vn = vv[nt];
        #pragma unroll
        for (int mt = 0; mt < 4; ++mt)
            #pragma unroll
            for (int r = 0; r < 4; ++r)
                srow[mt * 4 + r] += vn * fast_tanh(acc[nt][mt][r]);
    }
    #pragma unroll
    for (int i = 0; i < 16; ++i) {
        #pragma unroll
        for (int off = 1; off < 16; off <<= 1)
            srow[i] += __shfl_xor(srow[i], off, 64);
    }
    if ((l & 15) == 0) {
        int qd = l >> 4;
        #pragma unroll
        for (int mt = 0; mt < 4; ++mt)
            #pragma unroll
            for (int r = 0; r < 4; ++r)
                score_lds[(w << 6) + (mt << 4) + (qd << 2) + r] = srow[mt * 4 + r];
    }
    __syncthreads();

    if (t < 64) {   // wave 0: combine 8 wave-slices, exp, alpha, denom
        float sc = 0.f;
        #pragma unroll
        for (int ww = 0; ww < 8; ++ww) sc += score_lds[(ww << 6) + t];
        float e = __builtin_amdgcn_exp2f(sc * LOG2E);
        alpha_out[row0 + t] = e;
        escore[t] = e;
        float ssum = e;
        #pragma unroll
        for (int off = 1; off < 64; off <<= 1) ssum += __shfl_xor(ssum, off, 64);
        if (t == 0) atomicAdd(denom + b, ssum);
    }
    __syncthreads();

    // ---- context partial: wave w handles rows w*8..w*8+7, lane = h-octet ----
    float ca[8];
    #pragma unroll
    for (int j = 0; j < 8; ++j) ca[j] = 0.f;
    #pragma unroll
    for (int ii = 0; ii < 8; ++ii) {
        int m = (w << 3) + ii;
        float em = escore[m];
        bf16x8 av = *(const bf16x8*)(ldsA + (a_chunk(m, l) << 4));
        #pragma unroll
        for (int j = 0; j < 8; ++j) ca[j] += em * (float)av[j];
    }
    __syncthreads();                    // all A reads done -> reuse region
    float* part = (float*)ldsA;         // 512 threads x 8 floats, stride 9
    #pragma unroll
    for (int j = 0; j < 8; ++j) part[t * 9 + j] = ca[j];
    __syncthreads();
    {
        int h = t;                      // 512 threads = 512 h values
        int k8h = h >> 3, j = h & 7;
        float sum = 0.f;
        #pragma unroll
        for (int rg = 0; rg < 8; ++rg) sum += part[((rg << 6) | k8h) * 9 + j];
        atomicAdd(ctx_acc + ((long)b << 9) + h, sum);
    }
#undef LD_Q
#undef WR_Q
}

// ---------------------------------------------------------------------------
// K3: normalize both outputs by denom[b]
// ---------------------------------------------------------------------------
__global__ void normalize_kernel(const float* __restrict__ ctx_acc,
                                 const float* __restrict__ denom,
                                 float* __restrict__ out) {
    int i = blockIdx.x * 256 + threadIdx.x;
    if (i < 8192) {
        int b = i >> 9;
        out[i] = ctx_acc[i] / denom[b];
    } else if (i < 8192 + 131072) {
        int b = (i - 8192) >> 13;
        out[i] = out[i] / denom[b];
    }
}

extern "C" void kernel_launch(void* const* d_in, const int* in_sizes, int n_in,
                              void* d_out, int out_size, void* d_ws, size_t ws_size,
                              hipStream_t stream) {
    const float* enc   = (const float*)d_in[0];  // (16,8192,512)
    const float* query = (const float*)d_in[1];  // (16,512)
    const float* Wh    = (const float*)d_in[2];  // (512,512)
    const float* Wq    = (const float*)d_in[3];  // (512,512)
    const float* v     = (const float*)d_in[4];  // (512,)
    float* out = (float*)d_out;                  // [context 8192 | alpha 131072]

    char* ws = (char*)d_ws;
    float*  ctx_acc = (float*)ws;                // 8192 floats
    float*  denom   = (float*)(ws + 32768);      // 16 floats
    float*  qp      = (float*)(ws + 32832);      // 8192 floats
    __bf16* Wswz    = (__bf16*)(ws + 65600);     // 262144 bf16, 16B aligned

    prolog_kernel<<<2209, 256, 0, stream>>>(Wh, Wswz, query, Wq, qp,
                                            ctx_acc, denom);
    score_ctx_kernel<<<2048, 512, 0, stream>>>(enc, Wswz, qp, v,
                                               out + 8192, ctx_acc, denom);
    normalize_kernel<<<544, 256, 0, stream>>>(ctx_acc, denom, out);
}

// Round 3
// 445.526 us; speedup vs baseline: 1.0467x; 1.0216x over previous
//
#include <hip/hip_runtime.h>

typedef float  f32x4  __attribute__((ext_vector_type(4)));
typedef __bf16 bf16x8 __attribute__((ext_vector_type(8)));

#define LOG2E      1.4426950408889634f
#define TWO_LOG2E  2.8853900817779268f

__device__ __forceinline__ float fast_tanh(float x) {
    float e = __builtin_amdgcn_exp2f(x * TWO_LOG2E);
    return 1.0f - 2.0f * __builtin_amdgcn_rcpf(e + 1.0f);
}

// A-tile LDS swizzle: chunk(m, k8) for 16B chunk enc[m][k8*8..k8*8+7] (bf16)
//   high = (m>>4)*16 + (k8>>2)          (k8>>2 == s)
//   low6 = ((k8&3)<<4 | (m&15)) ^ ((k8>>2)&7) ^ (((k8&3)<<1)&7)
// MFMA read (lane l, tile mt, step s): low6 = l ^ (s&7) ^ (((l>>4)<<1)&7)
//   -> all 64 lanes distinct (conflict-free).
// Staging write / context read (k8 = lane, m fixed): bank-low3 =
//   (m&7) ^ ((l>>2)&7) ^ ((l&3)<<1) -> distinct within every 8-lane phase.
__device__ __forceinline__ int a_chunk(int m, int k8) {
    return (((m >> 4) * 16 + (k8 >> 2)) << 6) +
           ((((k8 & 3) << 4) | (m & 15)) ^ ((k8 >> 2) & 7) ^ (((k8 & 3) << 1) & 7));
}

// ---------------------------------------------------------------------------
// Prolog (one kernel, 2209 blocks x 256):
//   blocks [0,128)    : W_h fp32 -> bf16 swizzled B-fragment order
//   blocks [128,2176) : q_proj[b][o] = dot(query[b], Wq[o]) (one wave per pair)
//   blocks [2176,2209): zero ctx_acc (8192) + denom (16)
// ---------------------------------------------------------------------------
__global__ void prolog_kernel(const float* __restrict__ Wh,
                              __bf16* __restrict__ Wswz,
                              const float* __restrict__ query,
                              const float* __restrict__ Wq,
                              float* __restrict__ qp,
                              float* __restrict__ ctx_acc,
                              float* __restrict__ denom) {
    const int bid = blockIdx.x;
    const int t   = threadIdx.x;
    if (bid < 128) {
        int gid = (bid << 8) + t;              // 0..32767
        int n   = gid >> 6;
        int k8  = gid & 63;
        const float* g = Wh + ((long)n << 9) + (k8 << 3);
        f32x4 f0 = *(const f32x4*)g;
        f32x4 f1 = *(const f32x4*)(g + 4);
        bf16x8 val;
        val[0] = (__bf16)f0[0]; val[1] = (__bf16)f0[1];
        val[2] = (__bf16)f0[2]; val[3] = (__bf16)f0[3];
        val[4] = (__bf16)f1[0]; val[5] = (__bf16)f1[1];
        val[6] = (__bf16)f1[2]; val[7] = (__bf16)f1[3];
        int chunk = (((n >> 4) * 16 + (k8 >> 2)) << 6) + (((k8 & 3) << 4) | (n & 15));
        *(bf16x8*)(Wswz + ((long)chunk << 3)) = val;
    } else if (bid < 2176) {
        int pair = ((bid - 128) << 2) + (t >> 6);    // 0..8191 = b*512+o
        int l    = t & 63;
        int b    = pair >> 9;
        long o   = pair & 511;
        const f32x4* q  = (const f32x4*)(query + (b << 9) + (l << 3));
        const f32x4* wr = (const f32x4*)(Wq + (o << 9) + (l << 3));
        f32x4 a0 = q[0], a1 = q[1], w0 = wr[0], w1 = wr[1];
        float acc = a0[0]*w0[0] + a0[1]*w0[1] + a0[2]*w0[2] + a0[3]*w0[3]
                  + a1[0]*w1[0] + a1[1]*w1[1] + a1[2]*w1[2] + a1[3]*w1[3];
        #pragma unroll
        for (int off = 1; off < 64; off <<= 1) acc += __shfl_xor(acc, off, 64);
        if (l == 0) qp[pair] = acc;
    } else {
        int i = ((bid - 2176) << 8) + t;             // 0..8447
        if (i < 8192)      ctx_acc[i] = 0.f;
        else if (i < 8208) denom[i - 8192] = 0.f;
    }
}

// ---------------------------------------------------------------------------
// K2: fused scores + exp + context-partial.
// R3: block = 1024 threads (16 waves), 64 rows. Wave w owns N-slice
// [w*32, w*32+32) -> acc[2][4] = 32 AGPRs (was 64). The freed ~32 regs fund
// a double-buffered K-loop: af[2][4] ping-pong (next kstep's ds_reads issued
// before current MFMAs) + bfr[2][2] B-prefetch 2 deep (s=0,1 loaded before
// the barrier). Same 16 waves/CU occupancy (1 block/CU, LDS ~70KB), but
// K-loop latency now hidden by ILP instead of exposed per kstep.
// R1/R2 lesson: at acc=64 the 128-reg cap leaves 4 regs headroom -> any
// pipeline spills to scratch (WRITE_SIZE 4.6->176MB). acc=32 is the fix.
// ---------------------------------------------------------------------------
__global__ __launch_bounds__(1024, 4) void score_ctx_kernel(
    const float*  __restrict__ enc,
    const __bf16* __restrict__ Wswz,
    const float*  __restrict__ qp,
    const float*  __restrict__ v,
    float* __restrict__ alpha_out,   // (B*S) unnormalized e^score
    float* __restrict__ ctx_acc,     // (B*H) atomic accumulation
    float* __restrict__ denom)       // (B)   atomic accumulation
{
    __shared__ __align__(16) unsigned char ldsA[65536]; // 64 rows x 512 k bf16, swizzled
    __shared__ float score_lds[1024];                   // [wave 16][64 rows]
    __shared__ float escore[64];

    const int  t    = threadIdx.x;
    const int  w    = t >> 6;        // wave id 0..15 = N-slice owner
    const int  l    = t & 63;
    const long row0 = (long)blockIdx.x << 6;
    const int  b    = (int)(row0 >> 13);

    // ---- acc init = q_proj[b][n]; v fragment (wave slice = 32 N) ----
    f32x4 acc[2][4];     // [nt][mt]
    float vv[2];
    #pragma unroll
    for (int nt = 0; nt < 2; ++nt) {
        int n = (w << 5) + (nt << 4) + (l & 15);
        float q = qp[(b << 9) + n];
        vv[nt] = v[n];
        f32x4 qv = {q, q, q, q};
        #pragma unroll
        for (int mt = 0; mt < 4; ++mt) acc[nt][mt] = qv;
    }

    // ---- stage A: enc rows fp32 -> bf16 swizzled (4 chunks/thread) ----
    // wave w stages rows {w, w+16, w+32, w+48}, lane = k8 (coalesced 2KB/row)
    #pragma unroll
    for (int i = 0; i < 4; ++i) {
        int m  = (t >> 6) + (i << 4);
        int k8 = t & 63;
        const float* g = enc + ((row0 + m) << 9) + (k8 << 3);
        f32x4 f0 = *(const f32x4*)g;
        f32x4 f1 = *(const f32x4*)(g + 4);
        bf16x8 val;
        val[0] = (__bf16)f0[0]; val[1] = (__bf16)f0[1];
        val[2] = (__bf16)f0[2]; val[3] = (__bf16)f0[3];
        val[4] = (__bf16)f1[0]; val[5] = (__bf16)f1[1];
        val[6] = (__bf16)f1[2]; val[7] = (__bf16)f1[3];
        *(bf16x8*)(ldsA + (a_chunk(m, k8) << 4)) = val;
    }

    // ---- B-prefetch s=0,1 before the barrier (independent of staging) ----
    const bf16x8* Bg = (const bf16x8*)Wswz;
    const int j0 = w << 1;                      // first n-tile of this wave
    bf16x8 bfr[2][2];                           // [s-parity][nt]
    #pragma unroll
    for (int nt = 0; nt < 2; ++nt) {
        bfr[0][nt] = Bg[(((j0 + nt) << 4) + 0 << 6) + l];
        bfr[1][nt] = Bg[((((j0 + nt) << 4) + 1) << 6) + l];
    }

    __syncthreads();

    // ---- double-buffered K-loop ----
    bf16x8 af[2][4];                            // [s-parity][mt]
    {
        int lowr = l ^ 0 ^ (((l >> 4) << 1) & 7);
        #pragma unroll
        for (int mt = 0; mt < 4; ++mt)
            af[0][mt] = *(const bf16x8*)(ldsA + ((((mt << 4) << 6) + lowr) << 4));
    }
    #pragma unroll
    for (int s = 0; s < 16; ++s) {
        const int cur = s & 1, nxt = cur ^ 1;
        if (s < 15) {                           // issue next kstep's ds_reads
            int lowr = l ^ ((s + 1) & 7) ^ (((l >> 4) << 1) & 7);
            #pragma unroll
            for (int mt = 0; mt < 4; ++mt)
                af[nxt][mt] = *(const bf16x8*)(
                    ldsA + (((((mt << 4) + s + 1) << 6) + lowr) << 4));
        }
        #pragma unroll
        for (int nt = 0; nt < 2; ++nt)
            #pragma unroll
            for (int mt = 0; mt < 4; ++mt)
                acc[nt][mt] = __builtin_amdgcn_mfma_f32_16x16x32_bf16(
                    af[cur][mt], bfr[cur][nt], acc[nt][mt], 0, 0, 0);
        if (s + 2 < 16) {                       // refill this parity 2 ahead
            #pragma unroll
            for (int nt = 0; nt < 2; ++nt)
                bfr[cur][nt] = Bg[((((j0 + nt) << 4) + s + 2) << 6) + l];
        }
    }

    // ---- epilogue: per-row score partials over this wave's 32-col slice ----
    float srow[16];
    #pragma unroll
    for (int i = 0; i < 16; ++i) srow[i] = 0.f;
    #pragma unroll
    for (int nt = 0; nt < 2; ++nt) {
        float vn = vv[nt];
        #pragma unroll
        for (int mt = 0; mt < 4; ++mt)
            #pragma unroll
            for (int r = 0; r < 4; ++r)
                srow[mt * 4 + r] += vn * fast_tanh(acc[nt][mt][r]);
    }
    #pragma unroll
    for (int i = 0; i < 16; ++i) {
        #pragma unroll
        for (int off = 1; off < 16; off <<= 1)
            srow[i] += __shfl_xor(srow[i], off, 64);
    }
    if ((l & 15) == 0) {
        int qd = l >> 4;
        #pragma unroll
        for (int mt = 0; mt < 4; ++mt)
            #pragma unroll
            for (int r = 0; r < 4; ++r)
                score_lds[(w << 6) + (mt << 4) + (qd << 2) + r] = srow[mt * 4 + r];
    }
    __syncthreads();

    if (t < 64) {   // wave 0: combine 16 wave-slices, exp, alpha, denom
        float sc = 0.f;
        #pragma unroll
        for (int ww = 0; ww < 16; ++ww) sc += score_lds[(ww << 6) + t];
        float e = __builtin_amdgcn_exp2f(sc * LOG2E);
        alpha_out[row0 + t] = e;
        escore[t] = e;
        float ssum = e;
        #pragma unroll
        for (int off = 1; off < 64; off <<= 1) ssum += __shfl_xor(ssum, off, 64);
        if (t == 0) atomicAdd(denom + b, ssum);
    }
    __syncthreads();

    // ---- context partial: wave w handles rows w*4..w*4+3, lane = h-octet ----
    float ca[8];
    #pragma unroll
    for (int j = 0; j < 8; ++j) ca[j] = 0.f;
    #pragma unroll
    for (int ii = 0; ii < 4; ++ii) {
        int m = (w << 2) + ii;
        float em = escore[m];
        bf16x8 av = *(const bf16x8*)(ldsA + (a_chunk(m, l) << 4));
        #pragma unroll
        for (int j = 0; j < 8; ++j) ca[j] += em * (float)av[j];
    }
    __syncthreads();                    // all A reads done -> reuse region
    float* part = (float*)ldsA;         // 512 slots x 8 floats, stride 9 (18.4KB)
    if (t < 512) {                      // pass 1: waves 0..7 write
        #pragma unroll
        for (int j = 0; j < 8; ++j) part[t * 9 + j] = ca[j];
    }
    __syncthreads();
    if (t >= 512) {                     // pass 2: waves 8..15 accumulate
        int p = t - 512;
        #pragma unroll
        for (int j = 0; j < 8; ++j) part[p * 9 + j] += ca[j];
    }
    __syncthreads();
    if (t < 512) {                      // 512 threads = 512 h values
        int h = t;
        int k8h = h >> 3, j = h & 7;
        float sum = 0.f;
        #pragma unroll
        for (int rg = 0; rg < 8; ++rg) sum += part[((rg << 6) | k8h) * 9 + j];
        atomicAdd(ctx_acc + ((long)b << 9) + h, sum);
    }
}

// ---------------------------------------------------------------------------
// K3: normalize both outputs by denom[b]
// ---------------------------------------------------------------------------
__global__ void normalize_kernel(const float* __restrict__ ctx_acc,
                                 const float* __restrict__ denom,
                                 float* __restrict__ out) {
    int i = blockIdx.x * 256 + threadIdx.x;
    if (i < 8192) {
        int b = i >> 9;
        out[i] = ctx_acc[i] / denom[b];
    } else if (i < 8192 + 131072) {
        int b = (i - 8192) >> 13;
        out[i] = out[i] / denom[b];
    }
}

extern "C" void kernel_launch(void* const* d_in, const int* in_sizes, int n_in,
                              void* d_out, int out_size, void* d_ws, size_t ws_size,
                              hipStream_t stream) {
    const float* enc   = (const float*)d_in[0];  // (16,8192,512)
    const float* query = (const float*)d_in[1];  // (16,512)
    const float* Wh    = (const float*)d_in[2];  // (512,512)
    const float* Wq    = (const float*)d_in[3];  // (512,512)
    const float* v     = (const float*)d_in[4];  // (512,)
    float* out = (float*)d_out;                  // [context 8192 | alpha 131072]

    char* ws = (char*)d_ws;
    float*  ctx_acc = (float*)ws;                // 8192 floats
    float*  denom   = (float*)(ws + 32768);      // 16 floats
    float*  qp      = (float*)(ws + 32832);      // 8192 floats
    __bf16* Wswz    = (__bf16*)(ws + 65600);     // 262144 bf16, 16B aligned

    prolog_kernel<<<2209, 256, 0, stream>>>(Wh, Wswz, query, Wq, qp,
                                            ctx_acc, denom);
    score_ctx_kernel<<<2048, 1024, 0, stream>>>(enc, Wswz, qp, v,
                                                out + 8192, ctx_acc, denom);
    normalize_kernel<<<544, 256, 0, stream>>>(ctx_acc, denom, out);
}